// Round 5
// baseline (1584.832 us; speedup 1.0000x reference)
//
#include <hip/hip_runtime.h>

// NeuralBPDecoder: sparse BP over a 0.1%-dense parity matrix.
// Round 5 structure: ONE persistent cooperative kernel (256 blocks x 512).
// All cross-block state (beliefs, cmsg, CSR) goes through agent-scope
// relaxed atomics (sc1 -> coherent Infinity Cache, bypassing non-coherent
// per-XCD L2s), so phase barriers are a bare fetch_add(RELEASE)+acquire-poll
// on per-phase counters -- no L2 writeback, unlike grid.sync() (45us, r2)
// or kernel relaunch (~10us, r3). Batch-coalesced (entity,32) layout keeps
// every gather a 128B line read. Per-thread-owned items keep llr/sign/bel/
// counts in registers; epilogue fused into the final cv phase.

#define C_NUM 8192
#define V_NUM 16384
#define B_NUM 32
#define RW 64   // slots per check row (mean nnz 16.4; Binomial tail << 64)
#define CW 32   // slots per var col  (mean nnz  8.2; Binomial tail << 32)

#define NBLK 256
#define NTHR 512
#define NTH (NBLK * NTHR)   // 131072 threads

typedef unsigned short u16;
typedef unsigned int u32;
typedef unsigned long long u64;

#define ZERO_WORDS ((C_NUM * 4 + V_NUM * 4 + C_NUM * RW * 2 + V_NUM * CW * 2) / 4)

__device__ __forceinline__ float agent_ldf(const float* p) {
    return __hip_atomic_load(p, __ATOMIC_RELAXED, __HIP_MEMORY_SCOPE_AGENT);
}
__device__ __forceinline__ void agent_stf(float* p, float v) {
    __hip_atomic_store(p, v, __ATOMIC_RELAXED, __HIP_MEMORY_SCOPE_AGENT);
}
__device__ __forceinline__ u64 agent_ld64(const u64* p) {
    return __hip_atomic_load(p, __ATOMIC_RELAXED, __HIP_MEMORY_SCOPE_AGENT);
}
__device__ __forceinline__ int agent_ldi(const int* p) {
    return __hip_atomic_load(p, __ATOMIC_RELAXED, __HIP_MEMORY_SCOPE_AGENT);
}
__device__ __forceinline__ void agent_st32(u32* p, u32 v) {
    __hip_atomic_store(p, v, __ATOMIC_RELAXED, __HIP_MEMORY_SCOPE_AGENT);
}
__device__ __forceinline__ void agent_st16(u16* p, u16 v) {
    __hip_atomic_store(p, v, __ATOMIC_RELAXED, __HIP_MEMORY_SCOPE_AGENT);
}

// One counter per barrier id (64B apart); no reset race, no sense reversal.
__device__ __forceinline__ void grid_barrier(u32* bars, int id) {
    __syncthreads();
    if (threadIdx.x == 0) {
        __hip_atomic_fetch_add(&bars[id * 16], 1u, __ATOMIC_RELEASE,
                               __HIP_MEMORY_SCOPE_AGENT);
        while (__hip_atomic_load(&bars[id * 16], __ATOMIC_ACQUIRE,
                                 __HIP_MEMORY_SCOPE_AGENT) < (u32)NBLK)
            __builtin_amdgcn_s_sleep(1);
    }
    __syncthreads();
}

__device__ __forceinline__ float fast_tanh_half(float x) {
    // tanh(x/2) = sign(x) * (1 - e^-|x|) / (1 + e^-|x|)
    float ax = fabsf(x);
    float e = __expf(-ax);
    return copysignf((1.0f - e) / (1.0f + e), x);
}

__global__ __launch_bounds__(NTHR, 1)
void bp_fused(const float* __restrict__ H,      // (C, V)
              const float* __restrict__ synd,   // (B, C)
              const float* __restrict__ llr,    // (B, V)
              const float* __restrict__ w_vc_p,
              const float* __restrict__ w_cv_p,
              const float* __restrict__ damp_p,
              int* __restrict__ row_cnt, int* __restrict__ col_cnt,
              u16* __restrict__ row_idx, u16* __restrict__ col_idx,
              float* __restrict__ bel, float* __restrict__ cms,
              u32* __restrict__ bars,
              float* __restrict__ out) {        // (B, V)
    const int tid = blockIdx.x * NTHR + threadIdx.x;

    // ---- P0: zero CSR region (agent stores -> IF) ----
    {
        u32* zp = (u32*)row_cnt;   // row_cnt..col_idx contiguous (host layout)
        for (int t = tid; t < ZERO_WORDS; t += NTH) agent_st32(&zp[t], 0u);
    }
    // init beliefs for my 4 owned (v,b) items; cache llr in regs
    float llr_r[4], bel_r[4];
#pragma unroll
    for (int r = 0; r < 4; ++r) {
        int i = tid + r * NTH;          // V_NUM*B_NUM == 4*NTH
        int b = i & 31, v = i >> 5;
        float x = llr[b * V_NUM + v];
        llr_r[r] = x; bel_r[r] = x;
        agent_stf(&bel[i], x);
    }
    float ss_r[2];
#pragma unroll
    for (int r = 0; r < 2; ++r) {
        int i = tid + r * NTH;          // C_NUM*B_NUM == 2*NTH
        int b = i & 31, c = i >> 5;
        ss_r[r] = 1.0f - 2.0f * synd[b * C_NUM + c];
    }
    grid_barrier(bars, 0);

    // ---- P1: build CSR from dense H (512MB scan, 2 float4/iter for MLP) ----
    {
        const int total4 = C_NUM * V_NUM / 4;       // 33554432 = 256*NTH
        const float4* Hv = (const float4*)H;
        for (int t = tid; t < total4; t += 2 * NTH) {
            float4 h0 = Hv[t];
            float4 h1 = Hv[t + NTH];
#pragma unroll
            for (int half = 0; half < 2; ++half) {
                float4 hv = half ? h1 : h0;
                int base = (half ? (t + NTH) : t) * 4;
                float vals[4] = {hv.x, hv.y, hv.z, hv.w};
#pragma unroll
                for (int k = 0; k < 4; ++k) {
                    if (vals[k] != 0.0f) {
                        int ee = base + k;
                        int c = ee >> 14;            // V = 2^14
                        int v = ee & (V_NUM - 1);
                        int rs = atomicAdd(&row_cnt[c], 1);
                        if (rs < RW) agent_st16(&row_idx[c * RW + rs], (u16)v);
                        int cs = atomicAdd(&col_cnt[v], 1);
                        if (cs < CW) agent_st16(&col_idx[v * CW + cs], (u16)c);
                    }
                }
            }
        }
    }
    grid_barrier(bars, 1);

    // ---- cache per-item nnz counts in regs (fixed across iterations) ----
    int nrow_r[2];
#pragma unroll
    for (int r = 0; r < 2; ++r) {
        int c = (tid + r * NTH) >> 5;
        int n = agent_ldi(&row_cnt[c]);
        nrow_r[r] = n > RW ? RW : n;
    }
    int ncol_r[4];
#pragma unroll
    for (int r = 0; r < 4; ++r) {
        int v = (tid + r * NTH) >> 5;
        int n = agent_ldi(&col_cnt[v]);
        ncol_r[r] = n > CW ? CW : n;
    }
    const float wvc = w_vc_p[0];
    const float wcv = w_cv_p[0];
    const float d   = damp_p[0];

    // ---- P2: 15 BP iterations ----
    int barid = 2;
    for (int it = 0; it < 15; ++it) {
        // v->c : cms[c,b] = ss * tanh(0.5*wvc * sum bel[row])
#pragma unroll
        for (int r = 0; r < 2; ++r) {
            int i = tid + r * NTH;
            int b = i & 31, c = i >> 5;
            int n = nrow_r[r];
            const u64* q4 = (const u64*)(row_idx + c * RW);
            float sum = 0.0f;
            int k4 = (n + 3) >> 2;
            for (int p = 0; p < k4; ++p) {
                u64 q = agent_ld64(&q4[p]);       // 4 u16 idx, broadcast in b-group
                int j = 4 * p;
                int i0 = (int)(q & 0xFFFFu);
                int i1 = (int)((q >> 16) & 0xFFFFu);
                int i2 = (int)((q >> 32) & 0xFFFFu);
                int i3 = (int)(q >> 48);
                float s0 = agent_ldf(&bel[i0 * B_NUM + b]);  // zero-filled tail -> safe addr
                float s1 = agent_ldf(&bel[i1 * B_NUM + b]);
                float s2 = agent_ldf(&bel[i2 * B_NUM + b]);
                float s3 = agent_ldf(&bel[i3 * B_NUM + b]);
                sum += s0;
                sum += (j + 1 < n) ? s1 : 0.0f;
                sum += (j + 2 < n) ? s2 : 0.0f;
                sum += (j + 3 < n) ? s3 : 0.0f;
            }
            agent_stf(&cms[i], ss_r[r] * fast_tanh_half(wvc * sum));
        }
        grid_barrier(bars, barid++);

        // c->v : bel[v,b] = d*bel + (1-d)*(llr + wcv * sum cms[col]); own item
        bool last = (it == 14);
#pragma unroll
        for (int r = 0; r < 4; ++r) {
            int i = tid + r * NTH;
            int b = i & 31, v = i >> 5;
            int n = ncol_r[r];
            const u64* q4 = (const u64*)(col_idx + v * CW);
            float sum = 0.0f;
            int k4 = (n + 3) >> 2;
            for (int p = 0; p < k4; ++p) {
                u64 q = agent_ld64(&q4[p]);
                int j = 4 * p;
                int i0 = (int)(q & 0xFFFFu);
                int i1 = (int)((q >> 16) & 0xFFFFu);
                int i2 = (int)((q >> 32) & 0xFFFFu);
                int i3 = (int)(q >> 48);
                float s0 = agent_ldf(&cms[i0 * B_NUM + b]);
                float s1 = agent_ldf(&cms[i1 * B_NUM + b]);
                float s2 = agent_ldf(&cms[i2 * B_NUM + b]);
                float s3 = agent_ldf(&cms[i3 * B_NUM + b]);
                sum += s0;
                sum += (j + 1 < n) ? s1 : 0.0f;
                sum += (j + 2 < n) ? s2 : 0.0f;
                sum += (j + 3 < n) ? s3 : 0.0f;
            }
            float nb = d * bel_r[r] + (1.0f - d) * (llr_r[r] + wcv * sum);
            bel_r[r] = nb;
            if (!last) {
                agent_stf(&bel[i], nb);
            } else {
                // fused epilogue: out[b,v] = sigmoid(-bel); plain store,
                // kernel-end release makes it visible
                out[b * V_NUM + v] = 1.0f / (1.0f + __expf(nb));
            }
        }
        if (!last) grid_barrier(bars, barid++);
    }
}

extern "C" void kernel_launch(void* const* d_in, const int* in_sizes, int n_in,
                              void* d_out, int out_size, void* d_ws, size_t ws_size,
                              hipStream_t stream) {
    const float* synd = (const float*)d_in[0];   // (B, C)
    const float* H    = (const float*)d_in[1];   // (C, V)
    const float* llr  = (const float*)d_in[2];   // (B, V)
    const float* w_vc = (const float*)d_in[3];
    const float* w_cv = (const float*)d_in[4];
    const float* damp = (const float*)d_in[5];
    float* out = (float*)d_out;

    // ws layout: CSR region CONTIGUOUS (kernel zero-fills it as one span)
    char* ws = (char*)d_ws;
    size_t off = 0;
    int* row_cnt = (int*)(ws + off); off += (size_t)C_NUM * 4;        // 32 KB
    int* col_cnt = (int*)(ws + off); off += (size_t)V_NUM * 4;        // 64 KB
    u16* row_idx = (u16*)(ws + off); off += (size_t)C_NUM * RW * 2;   // 1 MB
    u16* col_idx = (u16*)(ws + off); off += (size_t)V_NUM * CW * 2;   // 1 MB
    float* bel = (float*)(ws + off); off += (size_t)V_NUM * B_NUM * 4; // 2 MB
    float* cms = (float*)(ws + off); off += (size_t)C_NUM * B_NUM * 4; // 1 MB
    u32* bars  = (u32*)(ws + off); off += 31 * 64;                     // 31 barrier lines

    // Only the barrier counters need host-side zeroing (ws arrives 0xAA)
    hipMemsetAsync(bars, 0, 31 * 64, stream);

    void* args[] = {
        (void*)&H, (void*)&synd, (void*)&llr,
        (void*)&w_vc, (void*)&w_cv, (void*)&damp,
        (void*)&row_cnt, (void*)&col_cnt, (void*)&row_idx, (void*)&col_idx,
        (void*)&bel, (void*)&cms, (void*)&bars, (void*)&out
    };
    hipLaunchCooperativeKernel((const void*)bp_fused,
                               dim3(NBLK), dim3(NTHR), args, 0, stream);
}

// Round 6
// 985.621 us; speedup vs baseline: 1.6080x; 1.6080x over previous
//
#include <hip/hip_runtime.h>

// NeuralBPDecoder: sparse BP over a 0.1%-dense parity matrix.
// Round 6: one persistent cooperative kernel (256 blocks x 1024). All
// cross-block data goes through agent-scope RELAXED atomics (sc1 ->
// coherent Infinity Cache, bypassing non-coherent per-XCD L2s) — proven
// correct AND fast in round 5. The round-5 killer was the barrier's
// acquire/release fences (agent acquire = buffer_inv, release = buffer_wbl2
// => ~30us per crossing, same storm as grid.sync). This barrier is
// RELAXED-only: __syncthreads() already drains vmcnt (all sc1 stores are at
// IF, the coherence point) before thread 0 signals arrival, so no cache
// maintenance is needed. Arrivals spread over 8 counters (256B apart) to
// avoid same-line atomic serialization.

#define C_NUM 8192
#define V_NUM 16384
#define B_NUM 32
#define RW 64   // slots per check row (mean nnz 16.4; Binomial tail << 64)
#define CW 32   // slots per var col  (mean nnz  8.2; Binomial tail << 32)

#define NBLK 256
#define NTHR 1024
#define NTH (NBLK * NTHR)   // 262144 threads, 16 waves/CU

typedef unsigned short u16;
typedef unsigned int u32;
typedef unsigned long long u64;

#define ZERO_WORDS ((C_NUM * 4 + V_NUM * 4 + C_NUM * RW * 2 + V_NUM * CW * 2) / 4)
#define NBAR 31
#define BAR_STRIDE 64              // u32s between counters (256 B)

__device__ __forceinline__ float agent_ldf(const float* p) {
    return __hip_atomic_load(p, __ATOMIC_RELAXED, __HIP_MEMORY_SCOPE_AGENT);
}
__device__ __forceinline__ void agent_stf(float* p, float v) {
    __hip_atomic_store(p, v, __ATOMIC_RELAXED, __HIP_MEMORY_SCOPE_AGENT);
}
__device__ __forceinline__ u64 agent_ld64(const u64* p) {
    return __hip_atomic_load(p, __ATOMIC_RELAXED, __HIP_MEMORY_SCOPE_AGENT);
}
__device__ __forceinline__ int agent_ldi(const int* p) {
    return __hip_atomic_load(p, __ATOMIC_RELAXED, __HIP_MEMORY_SCOPE_AGENT);
}
__device__ __forceinline__ void agent_st32(u32* p, u32 v) {
    __hip_atomic_store(p, v, __ATOMIC_RELAXED, __HIP_MEMORY_SCOPE_AGENT);
}
__device__ __forceinline__ void agent_st16(u16* p, u16 v) {
    __hip_atomic_store(p, v, __ATOMIC_RELAXED, __HIP_MEMORY_SCOPE_AGENT);
}

// Relaxed-only grid barrier: NO acquire/release (no buffer_inv/buffer_wbl2).
// Sound because all cross-block data uses sc1 (IF-coherent) accesses and
// __syncthreads drains vmcnt before arrival.
__device__ __forceinline__ void grid_barrier(u32* bars, int id) {
    __syncthreads();
    if (threadIdx.x == 0) {
        u32* base = bars + id * 8 * BAR_STRIDE;
        asm volatile("s_waitcnt vmcnt(0) lgkmcnt(0)" ::: "memory");
        __hip_atomic_fetch_add(base + (blockIdx.x & 7) * BAR_STRIDE, 1u,
                               __ATOMIC_RELAXED, __HIP_MEMORY_SCOPE_AGENT);
        u32 sum;
        do {
            sum = 0;
#pragma unroll
            for (int g = 0; g < 8; ++g)
                sum += __hip_atomic_load(base + g * BAR_STRIDE,
                                         __ATOMIC_RELAXED, __HIP_MEMORY_SCOPE_AGENT);
            if (sum < (u32)NBLK) __builtin_amdgcn_s_sleep(4);
        } while (sum < (u32)NBLK);
        asm volatile("" ::: "memory");
    }
    __syncthreads();
}

__device__ __forceinline__ float fast_tanh_half(float x) {
    // tanh(x/2) = sign(x) * (1 - e^-|x|) / (1 + e^-|x|)
    float ax = fabsf(x);
    float e = __expf(-ax);
    return copysignf((1.0f - e) / (1.0f + e), x);
}

__global__ __launch_bounds__(NTHR, 1)
void bp_fused(const float* __restrict__ H,      // (C, V)
              const float* __restrict__ synd,   // (B, C)
              const float* __restrict__ llr,    // (B, V)
              const float* __restrict__ w_vc_p,
              const float* __restrict__ w_cv_p,
              const float* __restrict__ damp_p,
              int* __restrict__ row_cnt, int* __restrict__ col_cnt,
              u16* __restrict__ row_idx, u16* __restrict__ col_idx,
              float* __restrict__ bel, float* __restrict__ cms,
              u32* __restrict__ bars,
              float* __restrict__ out) {        // (B, V)
    const int tid = blockIdx.x * NTHR + threadIdx.x;

    // ---- P0: zero CSR region (sc1 stores -> IF) + init state ----
    {
        u32* zp = (u32*)row_cnt;   // row_cnt..col_idx contiguous (host layout)
        for (int t = tid; t < ZERO_WORDS; t += NTH) agent_st32(&zp[t], 0u);
    }
    float llr_r[2], bel_r[2];
#pragma unroll
    for (int r = 0; r < 2; ++r) {
        int i = tid + r * NTH;          // V_NUM*B_NUM == 2*NTH
        int b = i & 31, v = i >> 5;
        float x = llr[b * V_NUM + v];
        llr_r[r] = x; bel_r[r] = x;
        agent_stf(&bel[i], x);
    }
    float ss_r;
    {
        int b = tid & 31, c = tid >> 5;  // C_NUM*B_NUM == NTH
        ss_r = 1.0f - 2.0f * synd[b * C_NUM + c];
    }
    grid_barrier(bars, 0);

    // ---- P1: build CSR from dense H (512MB scan; plain cached loads) ----
    {
        const int total4 = C_NUM * V_NUM / 4;       // 33554432 = 64 * 2*NTH
        const float4* Hv = (const float4*)H;
        for (int t = tid; t < total4; t += 2 * NTH) {
            float4 h0 = Hv[t];
            float4 h1 = Hv[t + NTH];
#pragma unroll
            for (int half = 0; half < 2; ++half) {
                float4 hv = half ? h1 : h0;
                int base = (half ? (t + NTH) : t) * 4;
                float vals[4] = {hv.x, hv.y, hv.z, hv.w};
#pragma unroll
                for (int k = 0; k < 4; ++k) {
                    if (vals[k] != 0.0f) {
                        int ee = base + k;
                        int c = ee >> 14;            // V = 2^14
                        int v = ee & (V_NUM - 1);
                        int rs = atomicAdd(&row_cnt[c], 1);   // device-scope
                        if (rs < RW) agent_st16(&row_idx[c * RW + rs], (u16)v);
                        int cs = atomicAdd(&col_cnt[v], 1);
                        if (cs < CW) agent_st16(&col_idx[v * CW + cs], (u16)c);
                    }
                }
            }
        }
    }
    grid_barrier(bars, 1);

    // ---- cache nnz counts (fixed across iterations) ----
    int nrow_r;
    {
        int n = agent_ldi(&row_cnt[tid >> 5]);
        nrow_r = n > RW ? RW : n;
    }
    int ncol_r[2];
#pragma unroll
    for (int r = 0; r < 2; ++r) {
        int n = agent_ldi(&col_cnt[(tid + r * NTH) >> 5]);
        ncol_r[r] = n > CW ? CW : n;
    }
    const float wvc = w_vc_p[0];
    const float wcv = w_cv_p[0];
    const float d   = damp_p[0];

    // ---- P2: 15 BP iterations ----
    int barid = 2;
    for (int it = 0; it < 15; ++it) {
        // v->c : cms[c,b] = ss * tanh(0.5*wvc * sum bel[row]); 1 item/thread
        {
            int b = tid & 31, c = tid >> 5;
            int n = nrow_r;
            const u64* q4 = (const u64*)(row_idx + c * RW);
            float sum = 0.0f;
            int k4 = (n + 3) >> 2;
            for (int p = 0; p < k4; ++p) {
                u64 q = agent_ld64(&q4[p]);   // 4 u16 idx, line-shared in b-group
                int j = 4 * p;
                int i0 = (int)(q & 0xFFFFu);
                int i1 = (int)((q >> 16) & 0xFFFFu);
                int i2 = (int)((q >> 32) & 0xFFFFu);
                int i3 = (int)(q >> 48);
                float s0 = agent_ldf(&bel[i0 * B_NUM + b]); // tail idx 0 -> safe
                float s1 = agent_ldf(&bel[i1 * B_NUM + b]);
                float s2 = agent_ldf(&bel[i2 * B_NUM + b]);
                float s3 = agent_ldf(&bel[i3 * B_NUM + b]);
                sum += s0;
                sum += (j + 1 < n) ? s1 : 0.0f;
                sum += (j + 2 < n) ? s2 : 0.0f;
                sum += (j + 3 < n) ? s3 : 0.0f;
            }
            agent_stf(&cms[tid], ss_r * fast_tanh_half(wvc * sum));
        }
        grid_barrier(bars, barid++);

        // c->v : bel = d*bel + (1-d)*(llr + wcv*sum cms[col]); 2 items/thread
        bool last = (it == 14);
#pragma unroll
        for (int r = 0; r < 2; ++r) {
            int i = tid + r * NTH;
            int b = i & 31, v = i >> 5;
            int n = ncol_r[r];
            const u64* q4 = (const u64*)(col_idx + v * CW);
            float sum = 0.0f;
            int k4 = (n + 3) >> 2;
            for (int p = 0; p < k4; ++p) {
                u64 q = agent_ld64(&q4[p]);
                int j = 4 * p;
                int i0 = (int)(q & 0xFFFFu);
                int i1 = (int)((q >> 16) & 0xFFFFu);
                int i2 = (int)((q >> 32) & 0xFFFFu);
                int i3 = (int)(q >> 48);
                float s0 = agent_ldf(&cms[i0 * B_NUM + b]);
                float s1 = agent_ldf(&cms[i1 * B_NUM + b]);
                float s2 = agent_ldf(&cms[i2 * B_NUM + b]);
                float s3 = agent_ldf(&cms[i3 * B_NUM + b]);
                sum += s0;
                sum += (j + 1 < n) ? s1 : 0.0f;
                sum += (j + 2 < n) ? s2 : 0.0f;
                sum += (j + 3 < n) ? s3 : 0.0f;
            }
            float nb = d * bel_r[r] + (1.0f - d) * (llr_r[r] + wcv * sum);
            bel_r[r] = nb;
            if (!last) {
                agent_stf(&bel[i], nb);
            } else {
                // fused epilogue; kernel-end release makes it visible
                out[b * V_NUM + v] = 1.0f / (1.0f + __expf(nb));
            }
        }
        if (!last) grid_barrier(bars, barid++);
    }
}

extern "C" void kernel_launch(void* const* d_in, const int* in_sizes, int n_in,
                              void* d_out, int out_size, void* d_ws, size_t ws_size,
                              hipStream_t stream) {
    const float* synd = (const float*)d_in[0];   // (B, C)
    const float* H    = (const float*)d_in[1];   // (C, V)
    const float* llr  = (const float*)d_in[2];   // (B, V)
    const float* w_vc = (const float*)d_in[3];
    const float* w_cv = (const float*)d_in[4];
    const float* damp = (const float*)d_in[5];
    float* out = (float*)d_out;

    // ws layout: CSR region CONTIGUOUS (kernel zero-fills it as one span)
    char* ws = (char*)d_ws;
    size_t off = 0;
    int* row_cnt = (int*)(ws + off); off += (size_t)C_NUM * 4;        // 32 KB
    int* col_cnt = (int*)(ws + off); off += (size_t)V_NUM * 4;        // 64 KB
    u16* row_idx = (u16*)(ws + off); off += (size_t)C_NUM * RW * 2;   // 1 MB
    u16* col_idx = (u16*)(ws + off); off += (size_t)V_NUM * CW * 2;   // 1 MB
    float* bel = (float*)(ws + off); off += (size_t)V_NUM * B_NUM * 4; // 2 MB
    float* cms = (float*)(ws + off); off += (size_t)C_NUM * B_NUM * 4; // 1 MB
    u32* bars  = (u32*)(ws + off); off += (size_t)NBAR * 8 * BAR_STRIDE * 4; // 63.5 KB

    // Only the barrier counters need host-side zeroing (ws arrives 0xAA)
    hipMemsetAsync(bars, 0, (size_t)NBAR * 8 * BAR_STRIDE * 4, stream);

    void* args[] = {
        (void*)&H, (void*)&synd, (void*)&llr,
        (void*)&w_vc, (void*)&w_cv, (void*)&damp,
        (void*)&row_cnt, (void*)&col_cnt, (void*)&row_idx, (void*)&col_idx,
        (void*)&bel, (void*)&cms, (void*)&bars, (void*)&out
    };
    hipLaunchCooperativeKernel((const void*)bp_fused,
                               dim3(NBLK), dim3(NTHR), args, 0, stream);
}